// Round 8
// baseline (299.627 us; speedup 1.0000x reference)
//
#include <hip/hip_runtime.h>
#include <math.h>

#define IDIM 1024
#define EDIM 256
#define NB 4
#define NT 2048
#define NROW 8192

typedef __attribute__((ext_vector_type(8))) short short8;
typedef __attribute__((ext_vector_type(4))) float f32x4;
typedef __attribute__((ext_vector_type(16))) float f32x16;

#define MFMA16(A,B,C) __builtin_amdgcn_mfma_f32_16x16x32_bf16(A,B,C,0,0,0)
#define MFMA32(A,B,C) __builtin_amdgcn_mfma_f32_32x32x16_bf16(A,B,C,0,0,0)
#define GLD16(gsrc, ldst) __builtin_amdgcn_global_load_lds( \
    (const __attribute__((address_space(1))) unsigned int*)(gsrc), \
    (__attribute__((address_space(3))) unsigned int*)(ldst), 16, 0, 0)

__device__ __forceinline__ unsigned short f2bf(float x){
    unsigned u = __builtin_bit_cast(unsigned, x);
    u += 0x7fffu + ((u >> 16) & 1u);
    return (unsigned short)(u >> 16);
}
__device__ __forceinline__ float bf2f(unsigned short h){
    unsigned u = ((unsigned)h) << 16;
    return __builtin_bit_cast(float, u);
}

// ---------------- split X -> hi/lo bf16 ----------------
__global__ __launch_bounds__(256) void split_x(
    const float* __restrict__ X, ushort* __restrict__ Xh, ushort* __restrict__ Xl)
{
    size_t i = ((size_t)blockIdx.x * 256 + threadIdx.x) * 8;
    float4 a = *(const float4*)(X + i);
    float4 b = *(const float4*)(X + i + 4);
    float v[8] = {a.x, a.y, a.z, a.w, b.x, b.y, b.z, b.w};
    union { ushort us[8]; uint4 u; } hi, lo;
    #pragma unroll
    for (int j = 0; j < 8; ++j) {
        unsigned short h = f2bf(v[j]);
        hi.us[j] = h;
        lo.us[j] = f2bf(v[j] - bf2f(h));
    }
    *(uint4*)(Xh + i) = hi.u;
    *(uint4*)(Xl + i) = lo.u;
}

// ---------------- split W -> W^T hi/lo bf16 ----------------
__global__ __launch_bounds__(256) void split_w(
    const float* __restrict__ Wq, const float* __restrict__ Wk, const float* __restrict__ Wv,
    ushort* __restrict__ Wqh, ushort* __restrict__ Wql,
    ushort* __restrict__ Wkh, ushort* __restrict__ Wkl,
    ushort* __restrict__ Wvh)
{
    int u = blockIdx.x * 256 + threadIdx.x;
    int z   = u >> 15;
    int rem = u & 32767;
    int ko  = rem >> 8;
    int e   = rem & 255;
    const float* W = (z == 0) ? Wq : (z == 1) ? Wk : Wv;
    ushort* Oh = (z == 0) ? Wqh : (z == 1) ? Wkh : Wvh;
    ushort* Ol = (z == 0) ? Wql : Wkl;
    union { ushort us[8]; uint4 v; } hi, lo;
    #pragma unroll
    for (int j = 0; j < 8; ++j) {
        float wv = W[(size_t)(ko * 8 + j) * 256 + e];
        unsigned short h = f2bf(wv);
        hi.us[j] = h;
        lo.us[j] = f2bf(wv - bf2f(h));
    }
    *(uint4*)(Oh + (size_t)e * 1024 + ko * 8) = hi.v;
    if (z < 2) *(uint4*)(Ol + (size_t)e * 1024 + ko * 8) = lo.v;
}

// ---------------- QKV projection: 128x128 tile, all-GLD16 staging ----------------
// __launch_bounds__(256,2): 256-reg budget. R7 omitted this -> default 1024-thread
// assumption capped regs at 128 -> acc[4][4](64 AGPR)+operands spilled to scratch.
__global__ __launch_bounds__(256, 2) void qkv_proj(
    const ushort* __restrict__ Xh, const ushort* __restrict__ Xl,
    const ushort* __restrict__ Whq, const ushort* __restrict__ Wlq,
    const ushort* __restrict__ Whk, const ushort* __restrict__ Wlk,
    const ushort* __restrict__ Whv,
    const float* __restrict__ bq, const float* __restrict__ bk, const float* __restrict__ bv,
    ushort* __restrict__ Qh, ushort* __restrict__ Ql,
    ushort* __restrict__ Kh, ushort* __restrict__ Kl,
    ushort* __restrict__ Vt)
{
    __shared__ ushort Ah[4096], Al[4096], Bh[4096], Bl[4096];  // unit = kq*128 + row

    const int tid = threadIdx.x;
    const int lane = tid & 63, w = tid >> 6;
    const int ln = tid & 15, quad = (tid >> 4) & 3;
    const int wr = w >> 1, wc = w & 1;
    const int z = blockIdx.z;
    const int n0 = blockIdx.x * 128, m0 = blockIdx.y * 128;
    const ushort* Wh = (z == 0) ? Whq : (z == 1) ? Whk : Whv;
    const ushort* Wl = (z == 0) ? Wlq : Wlk;

    f32x4 acc[4][4];
    #pragma unroll
    for (int mi = 0; mi < 4; ++mi)
        #pragma unroll
        for (int ni = 0; ni < 4; ++ni) acc[mi][ni] = (f32x4){0.f, 0.f, 0.f, 0.f};

    const ushort* a0 = Xh + (size_t)(m0 + lane) * IDIM + w * 8;
    const ushort* a1 = Xh + (size_t)(m0 + 64 + lane) * IDIM + w * 8;
    const ushort* a0l = Xl + (size_t)(m0 + lane) * IDIM + w * 8;
    const ushort* a1l = Xl + (size_t)(m0 + 64 + lane) * IDIM + w * 8;
    const ushort* b0 = Wh + (size_t)(n0 + lane) * IDIM + w * 8;
    const ushort* b1 = Wh + (size_t)(n0 + 64 + lane) * IDIM + w * 8;
    const ushort* b0l = Wl + (size_t)(n0 + lane) * IDIM + w * 8;
    const ushort* b1l = Wl + (size_t)(n0 + 64 + lane) * IDIM + w * 8;
    ushort* dA0 = Ah + (size_t)(w * 128) * 8;
    ushort* dA1 = Ah + (size_t)(w * 128 + 64) * 8;
    ushort* dA0l = Al + (size_t)(w * 128) * 8;
    ushort* dA1l = Al + (size_t)(w * 128 + 64) * 8;
    ushort* dB0 = Bh + (size_t)(w * 128) * 8;
    ushort* dB1 = Bh + (size_t)(w * 128 + 64) * 8;
    ushort* dB0l = Bl + (size_t)(w * 128) * 8;
    ushort* dB1l = Bl + (size_t)(w * 128 + 64) * 8;

    for (int kk = 0; kk < IDIM; kk += 32) {
        GLD16(a0 + kk, dA0);
        GLD16(a1 + kk, dA1);
        GLD16(b0 + kk, dB0);
        GLD16(b1 + kk, dB1);
        if (z < 2) {
            GLD16(a0l + kk, dA0l);
            GLD16(a1l + kk, dA1l);
            GLD16(b0l + kk, dB0l);
            GLD16(b1l + kk, dB1l);
        }
        __syncthreads();

        short8 ah[4], al[4], bh[4], bl[4];
        #pragma unroll
        for (int mi = 0; mi < 4; ++mi) {
            int au = quad * 128 + wr * 64 + mi * 16 + ln;
            ah[mi] = *(const short8*)(Ah + au * 8);
            if (z < 2) al[mi] = *(const short8*)(Al + au * 8);
        }
        #pragma unroll
        for (int ni = 0; ni < 4; ++ni) {
            int bu = quad * 128 + wc * 64 + ni * 16 + ln;
            bh[ni] = *(const short8*)(Bh + bu * 8);
            if (z < 2) bl[ni] = *(const short8*)(Bl + bu * 8);
        }
        if (z < 2) {
            #pragma unroll
            for (int ni = 0; ni < 4; ++ni)
                #pragma unroll
                for (int mi = 0; mi < 4; ++mi) {
                    acc[mi][ni] = MFMA16(ah[mi], bh[ni], acc[mi][ni]);
                    acc[mi][ni] = MFMA16(ah[mi], bl[ni], acc[mi][ni]);
                    acc[mi][ni] = MFMA16(al[mi], bh[ni], acc[mi][ni]);
                }
        } else {
            #pragma unroll
            for (int ni = 0; ni < 4; ++ni)
                #pragma unroll
                for (int mi = 0; mi < 4; ++mi)
                    acc[mi][ni] = MFMA16(ah[mi], bh[ni], acc[mi][ni]);
        }
        __syncthreads();
    }

    if (z < 2) {
        ushort* OH = (z == 0) ? Qh : Kh;
        ushort* OL = (z == 0) ? Ql : Kl;
        const float* bias = (z == 0) ? bq : bk;
        const float scale = (z == 0) ? 46.16624130844683f : 1.0f;  // 32*log2(e)
        #pragma unroll
        for (int ni = 0; ni < 4; ++ni) {
            int col = n0 + wc * 64 + ni * 16 + ln;
            float bb = bias[col];
            #pragma unroll
            for (int mi = 0; mi < 4; ++mi)
                #pragma unroll
                for (int r = 0; r < 4; ++r) {
                    int row = m0 + wr * 64 + mi * 16 + quad * 4 + r;
                    float v = (acc[mi][ni][r] + bb) * scale;
                    unsigned short hh = f2bf(v);
                    OH[(size_t)row * EDIM + col] = hh;
                    OL[(size_t)row * EDIM + col] = f2bf(v - bf2f(hh));
                }
        }
    } else {
        #pragma unroll
        for (int ni = 0; ni < 4; ++ni) {
            int col = n0 + wc * 64 + ni * 16 + ln;
            float bb = bv[col];
            #pragma unroll
            for (int mi = 0; mi < 4; ++mi) {
                int rowb = m0 + wr * 64 + mi * 16 + quad * 4;
                union { ushort us[4]; uint2 v; } pk;
                #pragma unroll
                for (int r = 0; r < 4; ++r) pk.us[r] = f2bf(acc[mi][ni][r] + bb);
                *(uint2*)(Vt + (size_t)col * NROW + rowb) = pk.v;  // V^T[e][row]
            }
        }
    }
}

// ---------------- attention v2: 32x32x16 MFMA, 2-wave blocks, 2 barriers/t ----------------
// Block = 64 q (2 waves x 32 q) x 512-kv quarter; t-tile = 32 kv, staged once
// (K hi/lo 32 KB + V 16 KB) then 64 MFMA. 512 blocks, 2 blocks/CU, 1 wave/SIMD.
__global__ __launch_bounds__(128, 1) void attn(
    const ushort* __restrict__ Qh, const ushort* __restrict__ Ql,
    const ushort* __restrict__ Kh, const ushort* __restrict__ Kl,
    const ushort* __restrict__ Vt, ushort* __restrict__ Op, float* __restrict__ mlbuf)
{
    __shared__ ushort KhiL[8192];   // unit u = eo*32 + c : K[kv0+c][eo*8..+8]
    __shared__ ushort KloL[8192];
    __shared__ ushort VsL[8192];    // unit u = koct*256 + e : V^T[e][kv0+koct*8..+8]
    __shared__ ushort Pall[2 * 1152];  // per-wave P slab [col(kv)][row(q)], col stride 36

    const int tid = threadIdx.x;
    const int lane = tid & 63, w = tid >> 6;
    const int lm = lane & 31, hh = lane >> 5;
    ushort* Pw = Pall + w * 1152;

    const int id = blockIdx.x;              // 512 = qt(32) x [b(4) x kvq(4)]
    const int cls = id & 15;
    const int b = cls >> 2, kvq = cls & 3;
    const int qt = id >> 4;
    const int qrow0w = b * NT + qt * 64 + w * 32;
    const int kvbase = b * NT + kvq * 512;

    // Q hi+lo fragments resident in registers (A-layout: m=lm, k=hh*8+j per 16-chunk)
    short8 qh[16], ql[16];
    #pragma unroll
    for (int kc = 0; kc < 16; ++kc) {
        size_t qoff = (size_t)(qrow0w + lm) * EDIM + kc * 16 + hh * 8;
        qh[kc] = *(const short8*)(Qh + qoff);
        ql[kc] = *(const short8*)(Ql + qoff);
    }

    float m_r[16], l_r[16];
    #pragma unroll
    for (int r = 0; r < 16; ++r) { m_r[r] = -3e38f; l_r[r] = 0.f; }
    f32x16 o[8];
    #pragma unroll
    for (int eb = 0; eb < 8; ++eb)
        #pragma unroll
        for (int r = 0; r < 16; ++r) o[eb][r] = 0.f;

    #pragma unroll 1
    for (int t = 0; t < 16; ++t) {
        const int kv0 = kvbase + t * 32;

        // ---- single stage phase: K hi/lo + V for this 32-kv chunk ----
        #pragma unroll
        for (int j = 0; j < 8; ++j) {
            int u = (w * 8 + j) * 64 + lane;
            int eo = u >> 5, c = u & 31;
            size_t koff = (size_t)(kv0 + c) * EDIM + eo * 8;
            GLD16(Kh + koff, KhiL + (size_t)(w * 8 + j) * 512);
            GLD16(Kl + koff, KloL + (size_t)(w * 8 + j) * 512);
        }
        #pragma unroll
        for (int j = 0; j < 8; ++j) {
            int u = (w * 8 + j) * 64 + lane;
            int koct = u >> 8, e = u & 255;
            GLD16(Vt + (size_t)e * NROW + kv0 + koct * 8,
                  VsL + (size_t)(w * 8 + j) * 512);
        }
        __syncthreads();

        // ---- S = Q'.K^T (32q x 32kv), split-bf16 ----
        f32x16 s;
        #pragma unroll
        for (int r = 0; r < 16; ++r) s[r] = 0.f;
        #pragma unroll
        for (int kc = 0; kc < 16; ++kc) {
            int bu = (kc * 2 + hh) * 32 + lm;
            short8 bh = *(const short8*)(KhiL + bu * 8);
            short8 bl = *(const short8*)(KloL + bu * 8);
            s = MFMA32(qh[kc], bh, s);
            s = MFMA32(qh[kc], bl, s);
            s = MFMA32(ql[kc], bh, s);
        }

        // ---- online softmax: reg r -> row (r&3)+8*(r>>2)+4*hh, col lm ----
        float alpha[16], p[16];
        #pragma unroll
        for (int r = 0; r < 16; ++r) {
            float mt = s[r];
            #pragma unroll
            for (int mask = 1; mask < 32; mask <<= 1)
                mt = fmaxf(mt, __shfl_xor(mt, mask));
            float mn = fmaxf(m_r[r], mt);
            alpha[r] = exp2f(m_r[r] - mn);
            m_r[r] = mn;
            float pv = exp2f(s[r] - mn);
            p[r] = pv;
            float ls = pv;
            #pragma unroll
            for (int mask = 1; mask < 32; mask <<= 1)
                ls += __shfl_xor(ls, mask);
            l_r[r] = l_r[r] * alpha[r] + ls;
        }
        // P slab write: [col=lm][rows rg*8+4hh ..+3] packed as b64
        #pragma unroll
        for (int rg = 0; rg < 4; ++rg) {
            union { ushort us[4]; uint2 v; } pk;
            #pragma unroll
            for (int r4 = 0; r4 < 4; ++r4) pk.us[r4] = f2bf(p[rg * 4 + r4]);
            *(uint2*)(Pw + lm * 36 + rg * 8 + hh * 4) = pk.v;
        }
        #pragma unroll
        for (int eb = 0; eb < 8; ++eb)
            #pragma unroll
            for (int r = 0; r < 16; ++r) o[eb][r] *= alpha[r];

        // ---- O += P.V : A-frag from slab (m=lm, k=c*16+hh*8+j), B from VsL ----
        #pragma unroll
        for (int c = 0; c < 2; ++c) {
            short8 ap;
            #pragma unroll
            for (int j = 0; j < 8; ++j)
                ((ushort*)&ap)[j] = Pw[(c * 16 + hh * 8 + j) * 36 + lm];
            #pragma unroll
            for (int eb = 0; eb < 8; ++eb) {
                short8 bv8 = *(const short8*)(VsL +
                    ((size_t)(c * 2 + hh) * 256 + eb * 32 + lm) * 8);
                o[eb] = MFMA32(ap, bv8, o[eb]);
            }
        }
        __syncthreads();
    }

    // ---- epilogue: bf16 partial + (m,l) ----
    const int pi = (b * 32 + qt) * 4 + kvq;
    if (lm == 0) {
        #pragma unroll
        for (int r = 0; r < 16; ++r) {
            int row = w * 32 + (r & 3) + 8 * (r >> 2) + 4 * hh;
            *(float2*)(mlbuf + ((size_t)pi * 64 + row) * 2) = make_float2(m_r[r], l_r[r]);
        }
    }
    #pragma unroll
    for (int r = 0; r < 16; ++r) {
        int row = w * 32 + (r & 3) + 8 * (r >> 2) + 4 * hh;
        ushort* dst = Op + (size_t)pi * 16384 + row * 256 + lm;
        #pragma unroll
        for (int eb = 0; eb < 8; ++eb)
            dst[eb * 32] = f2bf(o[eb][r]);
    }
}

// ---------------- final merge of 4 kv-quarter partials ----------------
__global__ __launch_bounds__(256) void attn_merge(
    const ushort* __restrict__ Op, const float* __restrict__ mlbuf, float* __restrict__ out)
{
    const int bid = blockIdx.x, t = threadIdx.x;   // 512 blocks: b(4) x qt(32) x rg(4)
    const int b = bid >> 7, qt = (bid >> 2) & 31, rg = bid & 3;
    const int row = rg * 16 + (t >> 4);
    const int e0 = (t & 15) * 16;
    const int pb = (b * 32 + qt) * 4;
    float mv[4], lv[4];
    float M = -3e38f;
    #pragma unroll
    for (int w2 = 0; w2 < 4; ++w2) {
        float2 ml = *(const float2*)(mlbuf + ((size_t)(pb + w2) * 64 + row) * 2);
        mv[w2] = ml.x; lv[w2] = ml.y;
        M = fmaxf(M, ml.x);
    }
    float sc[4], denom = 0.f;
    #pragma unroll
    for (int w2 = 0; w2 < 4; ++w2) {
        sc[w2] = exp2f(mv[w2] - M);
        denom += sc[w2] * lv[w2];
    }
    float inv = 1.0f / denom;
    #pragma unroll
    for (int w2 = 0; w2 < 4; ++w2) sc[w2] *= inv;

    float acc[16] = {};
    #pragma unroll
    for (int w2 = 0; w2 < 4; ++w2) {
        const ushort* src = Op + (size_t)(pb + w2) * 16384 + row * 256 + e0;
        #pragma unroll
        for (int c = 0; c < 2; ++c) {
            union { ushort us[8]; uint4 v; } u;
            u.v = *(const uint4*)(src + c * 8);
            #pragma unroll
            for (int j = 0; j < 8; ++j)
                acc[c * 8 + j] += sc[w2] * bf2f(u.us[j]);
        }
    }
    float* op = out + ((size_t)b * NT + qt * 64 + row) * EDIM + e0;
    #pragma unroll
    for (int g = 0; g < 4; ++g)
        *(float4*)(op + g * 4) = make_float4(acc[g*4], acc[g*4+1], acc[g*4+2], acc[g*4+3]);
}

extern "C" void kernel_launch(void* const* d_in, const int* in_sizes, int n_in,
                              void* d_out, int out_size, void* d_ws, size_t ws_size,
                              hipStream_t stream) {
    const float* x  = (const float*)d_in[0];
    const float* Wq = (const float*)d_in[1];
    const float* bq = (const float*)d_in[2];
    const float* Wk = (const float*)d_in[3];
    const float* bk = (const float*)d_in[4];
    const float* Wv = (const float*)d_in[5];
    const float* bv = (const float*)d_in[6];
    float* out = (float*)d_out;

    const size_t NX = (size_t)NROW * IDIM;           // 8.4M elems
    const size_t NE = (size_t)NB * NT * EDIM;        // 2M elems
    ushort* Xh = (ushort*)d_ws;                      // 16.8 MB
    ushort* Xl = Xh + NX;                            // 16.8 MB
    ushort* Qh = Xl + NX;
    ushort* Ql = Qh + NE;
    ushort* Kh = Ql + NE;
    ushort* Kl = Kh + NE;
    ushort* Vt = Kl + NE;                            // [256][8192]
    ushort* Wqh = Vt + NE;
    ushort* Wql = Wqh + 256 * 1024;
    ushort* Wkh = Wql + 256 * 1024;
    ushort* Wkl = Wkh + 256 * 1024;
    ushort* Wvh = Wkl + 256 * 1024;                  // total ~56.2 MB
    // Op/mlb alias Xh/Xl (dead after qkv_proj; same-stream ordering)
    ushort* Op  = Xh;                                // 512 x 64 x 256 bf16 (16.8 MB)
    float*  mlb = (float*)(Xh + (size_t)512 * 16384);

    split_x<<<4096, 256, 0, stream>>>(x, Xh, Xl);
    split_w<<<384, 256, 0, stream>>>(Wq, Wk, Wv, Wqh, Wql, Wkh, Wkl, Wvh);
    qkv_proj<<<dim3(2, 64, 3), 256, 0, stream>>>(Xh, Xl, Wqh, Wql, Wkh, Wkl, Wvh,
                                                 bq, bk, bv, Qh, Ql, Kh, Kl, Vt);
    attn<<<512, 128, 0, stream>>>(Qh, Ql, Kh, Kl, Vt, Op, mlb);
    attn_merge<<<512, 256, 0, stream>>>(Op, mlb, out);
}

// Round 9
// 232.385 us; speedup vs baseline: 1.2894x; 1.2894x over previous
//
#include <hip/hip_runtime.h>
#include <math.h>

#define IDIM 1024
#define EDIM 256
#define NB 4
#define NT 2048
#define NROW 8192

typedef __attribute__((ext_vector_type(8))) short short8;
typedef __attribute__((ext_vector_type(4))) float f32x4;

#define MFMA16(A,B,C) __builtin_amdgcn_mfma_f32_16x16x32_bf16(A,B,C,0,0,0)
#define GLD16(gsrc, ldst) __builtin_amdgcn_global_load_lds( \
    (const __attribute__((address_space(1))) unsigned int*)(gsrc), \
    (__attribute__((address_space(3))) unsigned int*)(ldst), 16, 0, 0)

__device__ __forceinline__ unsigned short f2bf(float x){
    unsigned u = __builtin_bit_cast(unsigned, x);
    u += 0x7fffu + ((u >> 16) & 1u);
    return (unsigned short)(u >> 16);
}
__device__ __forceinline__ float bf2f(unsigned short h){
    unsigned u = ((unsigned)h) << 16;
    return __builtin_bit_cast(float, u);
}

// ---------------- split X -> hi/lo bf16 ----------------
__global__ __launch_bounds__(256) void split_x(
    const float* __restrict__ X, ushort* __restrict__ Xh, ushort* __restrict__ Xl)
{
    size_t i = ((size_t)blockIdx.x * 256 + threadIdx.x) * 8;
    float4 a = *(const float4*)(X + i);
    float4 b = *(const float4*)(X + i + 4);
    float v[8] = {a.x, a.y, a.z, a.w, b.x, b.y, b.z, b.w};
    union { ushort us[8]; uint4 u; } hi, lo;
    #pragma unroll
    for (int j = 0; j < 8; ++j) {
        unsigned short h = f2bf(v[j]);
        hi.us[j] = h;
        lo.us[j] = f2bf(v[j] - bf2f(h));
    }
    *(uint4*)(Xh + i) = hi.u;
    *(uint4*)(Xl + i) = lo.u;
}

// ---------------- split W -> W^T hi/lo bf16 ----------------
__global__ __launch_bounds__(256) void split_w(
    const float* __restrict__ Wq, const float* __restrict__ Wk, const float* __restrict__ Wv,
    ushort* __restrict__ Wqh, ushort* __restrict__ Wql,
    ushort* __restrict__ Wkh, ushort* __restrict__ Wkl,
    ushort* __restrict__ Wvh)
{
    int u = blockIdx.x * 256 + threadIdx.x;
    int z   = u >> 15;
    int rem = u & 32767;
    int ko  = rem >> 8;
    int e   = rem & 255;
    const float* W = (z == 0) ? Wq : (z == 1) ? Wk : Wv;
    ushort* Oh = (z == 0) ? Wqh : (z == 1) ? Wkh : Wvh;
    ushort* Ol = (z == 0) ? Wql : Wkl;
    union { ushort us[8]; uint4 v; } hi, lo;
    #pragma unroll
    for (int j = 0; j < 8; ++j) {
        float wv = W[(size_t)(ko * 8 + j) * 256 + e];
        unsigned short h = f2bf(wv);
        hi.us[j] = h;
        lo.us[j] = f2bf(wv - bf2f(h));
    }
    *(uint4*)(Oh + (size_t)e * 1024 + ko * 8) = hi.v;
    if (z < 2) *(uint4*)(Ol + (size_t)e * 1024 + ko * 8) = lo.v;
}

// ---------------- QKV projection: 128m x 64n tiles, 768 blocks (3/CU), all-GLD16 ----------------
// Wave w owns m-strip w*32 (2 MFMA rows) x all 64 n (4 tiles): acc 2x4, 24 MFMA/k-step (z<2).
__global__ __launch_bounds__(256, 3) void qkv_proj(
    const ushort* __restrict__ Xh, const ushort* __restrict__ Xl,
    const ushort* __restrict__ Whq, const ushort* __restrict__ Wlq,
    const ushort* __restrict__ Whk, const ushort* __restrict__ Wlk,
    const ushort* __restrict__ Whv,
    const float* __restrict__ bq, const float* __restrict__ bk, const float* __restrict__ bv,
    ushort* __restrict__ Qh, ushort* __restrict__ Ql,
    ushort* __restrict__ Kh, ushort* __restrict__ Kl,
    ushort* __restrict__ Vt)
{
    __shared__ ushort Ah[4096], Al[4096];   // unit = kq*128 + row (128 m-rows)
    __shared__ ushort Bh[2048], Bl[2048];   // unit = kq*64 + row  (64 n-rows)

    const int tid = threadIdx.x;
    const int lane = tid & 63, w = tid >> 6;
    const int ln = tid & 15, quad = (tid >> 4) & 3;
    const int z = blockIdx.z;
    const int n0 = blockIdx.x * 64, m0 = blockIdx.y * 128;
    const ushort* Wh = (z == 0) ? Whq : (z == 1) ? Whk : Whv;
    const ushort* Wl = (z == 0) ? Wlq : Wlk;

    f32x4 acc[2][4];
    #pragma unroll
    for (int mi = 0; mi < 2; ++mi)
        #pragma unroll
        for (int ni = 0; ni < 4; ++ni) acc[mi][ni] = (f32x4){0.f, 0.f, 0.f, 0.f};

    // wave w stages k-octet kq=w for all rows (A: 2 calls hi [+2 lo], B: 1 [+1])
    const ushort* a0 = Xh + (size_t)(m0 + lane) * IDIM + w * 8;
    const ushort* a1 = Xh + (size_t)(m0 + 64 + lane) * IDIM + w * 8;
    const ushort* a0l = Xl + (size_t)(m0 + lane) * IDIM + w * 8;
    const ushort* a1l = Xl + (size_t)(m0 + 64 + lane) * IDIM + w * 8;
    const ushort* b0 = Wh + (size_t)(n0 + lane) * IDIM + w * 8;
    const ushort* b0l = Wl + (size_t)(n0 + lane) * IDIM + w * 8;
    ushort* dA0 = Ah + (size_t)(w * 128) * 8;
    ushort* dA1 = Ah + (size_t)(w * 128 + 64) * 8;
    ushort* dA0l = Al + (size_t)(w * 128) * 8;
    ushort* dA1l = Al + (size_t)(w * 128 + 64) * 8;
    ushort* dB0 = Bh + (size_t)(w * 64) * 8;
    ushort* dB0l = Bl + (size_t)(w * 64) * 8;

    for (int kk = 0; kk < IDIM; kk += 32) {
        GLD16(a0 + kk, dA0);
        GLD16(a1 + kk, dA1);
        GLD16(b0 + kk, dB0);
        if (z < 2) {
            GLD16(a0l + kk, dA0l);
            GLD16(a1l + kk, dA1l);
            GLD16(b0l + kk, dB0l);
        }
        __syncthreads();

        short8 ah[2], al[2], bh[4], bl[4];
        #pragma unroll
        for (int mi = 0; mi < 2; ++mi) {
            int au = quad * 128 + w * 32 + mi * 16 + ln;
            ah[mi] = *(const short8*)(Ah + au * 8);
            if (z < 2) al[mi] = *(const short8*)(Al + au * 8);
        }
        #pragma unroll
        for (int ni = 0; ni < 4; ++ni) {
            int bu = quad * 64 + ni * 16 + ln;
            bh[ni] = *(const short8*)(Bh + bu * 8);
            if (z < 2) bl[ni] = *(const short8*)(Bl + bu * 8);
        }
        if (z < 2) {
            #pragma unroll
            for (int ni = 0; ni < 4; ++ni)
                #pragma unroll
                for (int mi = 0; mi < 2; ++mi) {
                    acc[mi][ni] = MFMA16(ah[mi], bh[ni], acc[mi][ni]);
                    acc[mi][ni] = MFMA16(ah[mi], bl[ni], acc[mi][ni]);
                    acc[mi][ni] = MFMA16(al[mi], bh[ni], acc[mi][ni]);
                }
        } else {
            #pragma unroll
            for (int ni = 0; ni < 4; ++ni)
                #pragma unroll
                for (int mi = 0; mi < 2; ++mi)
                    acc[mi][ni] = MFMA16(ah[mi], bh[ni], acc[mi][ni]);
        }
        __syncthreads();
    }

    if (z < 2) {
        ushort* OH = (z == 0) ? Qh : Kh;
        ushort* OL = (z == 0) ? Ql : Kl;
        const float* bias = (z == 0) ? bq : bk;
        const float scale = (z == 0) ? 46.16624130844683f : 1.0f;  // 32*log2(e)
        #pragma unroll
        for (int ni = 0; ni < 4; ++ni) {
            int col = n0 + ni * 16 + ln;
            float bb = bias[col];
            #pragma unroll
            for (int mi = 0; mi < 2; ++mi)
                #pragma unroll
                for (int r = 0; r < 4; ++r) {
                    int row = m0 + w * 32 + mi * 16 + quad * 4 + r;
                    float v = (acc[mi][ni][r] + bb) * scale;
                    unsigned short hh = f2bf(v);
                    OH[(size_t)row * EDIM + col] = hh;
                    OL[(size_t)row * EDIM + col] = f2bf(v - bf2f(hh));
                }
        }
    } else {
        #pragma unroll
        for (int ni = 0; ni < 4; ++ni) {
            int col = n0 + ni * 16 + ln;
            float bb = bv[col];
            #pragma unroll
            for (int mi = 0; mi < 2; ++mi) {
                int rowb = m0 + w * 32 + mi * 16 + quad * 4;
                union { ushort us[4]; uint2 v; } pk;
                #pragma unroll
                for (int r = 0; r < 4; ++r) pk.us[r] = f2bf(acc[mi][ni][r] + bb);
                *(uint2*)(Vt + (size_t)col * NROW + rowb) = pk.v;  // V^T[e][row]
            }
        }
    }
}

// ---------------- attention (R6 known-good): block = 64 q x 512 kv, GLD16-staged K/V ----------------
__global__ __launch_bounds__(256, 2) void attn(
    const ushort* __restrict__ Qh, const ushort* __restrict__ Ql,
    const ushort* __restrict__ Kh, const ushort* __restrict__ Kl,
    const ushort* __restrict__ Vt, ushort* __restrict__ Op, float* __restrict__ mlbuf)
{
    __shared__ ushort KVbuf[4096];     // 8 KB: K chunk (hi 4K @0, lo 4K @2048u) / V chunk
    __shared__ ushort Qls[16384];      // 32 KB: wave w at w*4096 (unit = ko*16+ln)
    __shared__ ushort Pall[4 * 1088];  // per-wave P slab (unit = ko*17+row)

    const int tid = threadIdx.x;
    const int lane = tid & 63;
    const int ln = tid & 15, quad = (tid >> 4) & 3, w = tid >> 6;
    ushort* Qls_w = Qls + w * 4096;
    ushort* Pw = Pall + w * 1088;

    const int id = blockIdx.x;              // 512 = qt(32) x [b(4) x kvq(4)]
    const int cls = id & 15;
    const int b = cls >> 2, kvq = cls & 3;
    const int qt = id >> 4;
    const int qrow0w = b * NT + qt * 64 + w * 16;
    const int kvbase = b * NT + kvq * 512;

    short8 qh8[8];
    #pragma unroll
    for (int kc = 0; kc < 8; ++kc)
        qh8[kc] = *(const short8*)(Qh + (size_t)(qrow0w + ln) * EDIM + kc * 32 + quad * 8);
    #pragma unroll
    for (int i = 0; i < 8; ++i) {
        int u = i * 64 + lane;
        int ko = u >> 4, ln2 = u & 15;
        *(uint4*)(Qls_w + u * 8) =
            *(const uint4*)(Ql + (size_t)(qrow0w + ln2) * EDIM + ko * 8);
    }

    float m_r[4], l_r[4];
    #pragma unroll
    for (int r = 0; r < 4; ++r) { m_r[r] = -3e38f; l_r[r] = 0.f; }
    f32x4 o[16];
    #pragma unroll
    for (int ni = 0; ni < 16; ++ni) o[ni] = (f32x4){0.f, 0.f, 0.f, 0.f};

    for (int t = 0; t < 8; ++t) {
        const int kv0 = kvbase + t * 64;
        f32x4 s[4];
        #pragma unroll
        for (int ni = 0; ni < 4; ++ni) s[ni] = (f32x4){0.f, 0.f, 0.f, 0.f};

        #pragma unroll
        for (int kc = 0; kc < 8; ++kc) {
            size_t goff = (size_t)(kv0 + w * 16 + (lane & 15)) * EDIM
                          + kc * 32 + (lane >> 4) * 8;
            GLD16(Kh + goff, KVbuf + w * 512);
            GLD16(Kl + goff, KVbuf + 2048 + w * 512);
            __syncthreads();
            short8 ql8 = *(const short8*)(Qls_w + ((kc * 4 + quad) * 16 + ln) * 8);
            #pragma unroll
            for (int ni = 0; ni < 4; ++ni) {
                short8 bh = *(const short8*)(KVbuf + (ni * 64 + quad * 16 + ln) * 8);
                short8 bl = *(const short8*)(KVbuf + 2048 + (ni * 64 + quad * 16 + ln) * 8);
                s[ni] = MFMA16(qh8[kc], bh, s[ni]);
                s[ni] = MFMA16(qh8[kc], bl, s[ni]);
                s[ni] = MFMA16(ql8, bh, s[ni]);
            }
            __syncthreads();
        }

        float mt[4];
        #pragma unroll
        for (int r = 0; r < 4; ++r)
            mt[r] = fmaxf(fmaxf(s[0][r], s[1][r]), fmaxf(s[2][r], s[3][r]));
        #pragma unroll
        for (int mask = 1; mask < 16; mask <<= 1)
            #pragma unroll
            for (int r = 0; r < 4; ++r)
                mt[r] = fmaxf(mt[r], __shfl_xor(mt[r], mask));
        float alpha[4];
        #pragma unroll
        for (int r = 0; r < 4; ++r) {
            float mn = fmaxf(m_r[r], mt[r]);
            alpha[r] = exp2f(m_r[r] - mn);
            m_r[r] = mn;
        }
        float ls[4] = {0.f, 0.f, 0.f, 0.f};
        #pragma unroll
        for (int ni = 0; ni < 4; ++ni) {
            int colb = ni * 16 + ln;
            #pragma unroll
            for (int r = 0; r < 4; ++r) {
                float p = exp2f(s[ni][r] - m_r[r]);
                ls[r] += p;
                Pw[((colb >> 3) * 17 + quad * 4 + r) * 8 + (colb & 7)] = f2bf(p);
            }
        }
        #pragma unroll
        for (int mask = 1; mask < 16; mask <<= 1)
            #pragma unroll
            for (int r = 0; r < 4; ++r)
                ls[r] += __shfl_xor(ls[r], mask);
        #pragma unroll
        for (int r = 0; r < 4; ++r) l_r[r] = l_r[r] * alpha[r] + ls[r];
        #pragma unroll
        for (int ni = 0; ni < 16; ++ni)
            #pragma unroll
            for (int r = 0; r < 4; ++r) o[ni][r] *= alpha[r];

        short8 apk0 = *(const short8*)(Pw + (quad * 17 + ln) * 8);
        short8 apk1 = *(const short8*)(Pw + ((4 + quad) * 17 + ln) * 8);
        #pragma unroll
        for (int vs = 0; vs < 4; ++vs) {
            size_t gv = (size_t)(vs * 64 + w * 16 + (lane & 15)) * NROW
                        + kv0 + (lane >> 4) * 8;
            GLD16(Vt + gv, KVbuf + w * 1024);
            GLD16(Vt + gv + 32, KVbuf + w * 1024 + 512);
            __syncthreads();
            #pragma unroll
            for (int ni = 0; ni < 4; ++ni) {
                short8 v0 = *(const short8*)(KVbuf + (ni * 128 + quad * 16 + ln) * 8);
                short8 v1 = *(const short8*)(KVbuf + (ni * 128 + 64 + quad * 16 + ln) * 8);
                o[vs * 4 + ni] = MFMA16(apk0, v0, o[vs * 4 + ni]);
                o[vs * 4 + ni] = MFMA16(apk1, v1, o[vs * 4 + ni]);
            }
            __syncthreads();
        }
    }

    const int p = (b * 32 + qt) * 4 + kvq;
    if (ln == 0) {
        #pragma unroll
        for (int r = 0; r < 4; ++r) {
            int row = w * 16 + quad * 4 + r;
            *(float2*)(mlbuf + ((size_t)p * 64 + row) * 2) = make_float2(m_r[r], l_r[r]);
        }
    }
    #pragma unroll
    for (int ni = 0; ni < 16; ++ni)
        #pragma unroll
        for (int r = 0; r < 4; ++r) {
            int row = w * 16 + quad * 4 + r;
            Op[(size_t)p * 16384 + row * 256 + ni * 16 + ln] = f2bf(o[ni][r]);
        }
}

// ---------------- final merge of 4 kv-quarter partials ----------------
__global__ __launch_bounds__(256) void attn_merge(
    const ushort* __restrict__ Op, const float* __restrict__ mlbuf, float* __restrict__ out)
{
    const int bid = blockIdx.x, t = threadIdx.x;   // 512 blocks: b(4) x qt(32) x rg(4)
    const int b = bid >> 7, qt = (bid >> 2) & 31, rg = bid & 3;
    const int row = rg * 16 + (t >> 4);
    const int e0 = (t & 15) * 16;
    const int pb = (b * 32 + qt) * 4;
    float mv[4], lv[4];
    float M = -3e38f;
    #pragma unroll
    for (int w2 = 0; w2 < 4; ++w2) {
        float2 ml = *(const float2*)(mlbuf + ((size_t)(pb + w2) * 64 + row) * 2);
        mv[w2] = ml.x; lv[w2] = ml.y;
        M = fmaxf(M, ml.x);
    }
    float sc[4], denom = 0.f;
    #pragma unroll
    for (int w2 = 0; w2 < 4; ++w2) {
        sc[w2] = exp2f(mv[w2] - M);
        denom += sc[w2] * lv[w2];
    }
    float inv = 1.0f / denom;
    #pragma unroll
    for (int w2 = 0; w2 < 4; ++w2) sc[w2] *= inv;

    float acc[16] = {};
    #pragma unroll
    for (int w2 = 0; w2 < 4; ++w2) {
        const ushort* src = Op + (size_t)(pb + w2) * 16384 + row * 256 + e0;
        #pragma unroll
        for (int c = 0; c < 2; ++c) {
            union { ushort us[8]; uint4 v; } u;
            u.v = *(const uint4*)(src + c * 8);
            #pragma unroll
            for (int j = 0; j < 8; ++j)
                acc[c * 8 + j] += sc[w2] * bf2f(u.us[j]);
        }
    }
    float* op = out + ((size_t)b * NT + qt * 64 + row) * EDIM + e0;
    #pragma unroll
    for (int g = 0; g < 4; ++g)
        *(float4*)(op + g * 4) = make_float4(acc[g*4], acc[g*4+1], acc[g*4+2], acc[g*4+3]);
}

extern "C" void kernel_launch(void* const* d_in, const int* in_sizes, int n_in,
                              void* d_out, int out_size, void* d_ws, size_t ws_size,
                              hipStream_t stream) {
    const float* x  = (const float*)d_in[0];
    const float* Wq = (const float*)d_in[1];
    const float* bq = (const float*)d_in[2];
    const float* Wk = (const float*)d_in[3];
    const float* bk = (const float*)d_in[4];
    const float* Wv = (const float*)d_in[5];
    const float* bv = (const float*)d_in[6];
    float* out = (float*)d_out;

    const size_t NX = (size_t)NROW * IDIM;           // 8.4M elems
    const size_t NE = (size_t)NB * NT * EDIM;        // 2M elems
    ushort* Xh = (ushort*)d_ws;                      // 16.8 MB
    ushort* Xl = Xh + NX;                            // 16.8 MB
    ushort* Qh = Xl + NX;
    ushort* Ql = Qh + NE;
    ushort* Kh = Ql + NE;
    ushort* Kl = Kh + NE;
    ushort* Vt = Kl + NE;                            // [256][8192]
    ushort* Wqh = Vt + NE;
    ushort* Wql = Wqh + 256 * 1024;
    ushort* Wkh = Wql + 256 * 1024;
    ushort* Wkl = Wkh + 256 * 1024;
    ushort* Wvh = Wkl + 256 * 1024;                  // total ~56.2 MB
    // Op/mlb alias Xh/Xl (dead after qkv_proj; same-stream ordering)
    ushort* Op  = Xh;                                // 512 x 64 x 256 bf16 (16.8 MB)
    float*  mlb = (float*)(Xh + (size_t)512 * 16384);

    split_x<<<4096, 256, 0, stream>>>(x, Xh, Xl);
    split_w<<<384, 256, 0, stream>>>(Wq, Wk, Wv, Wqh, Wql, Wkh, Wkl, Wvh);
    qkv_proj<<<dim3(4, 64, 3), 256, 0, stream>>>(Xh, Xl, Wqh, Wql, Wkh, Wkl, Wvh,
                                                 bq, bk, bv, Qh, Ql, Kh, Kl, Vt);
    attn<<<512, 256, 0, stream>>>(Qh, Ql, Kh, Kl, Vt, Op, mlb);
    attn_merge<<<512, 256, 0, stream>>>(Op, mlb, out);
}

// Round 10
// 220.646 us; speedup vs baseline: 1.3580x; 1.0532x over previous
//
#include <hip/hip_runtime.h>
#include <math.h>

#define IDIM 1024
#define EDIM 256
#define NB 4
#define NT 2048
#define NROW 8192

typedef __attribute__((ext_vector_type(8))) short short8;
typedef __attribute__((ext_vector_type(4))) float f32x4;

#define MFMA16(A,B,C) __builtin_amdgcn_mfma_f32_16x16x32_bf16(A,B,C,0,0,0)
#define GLD16(gsrc, ldst) __builtin_amdgcn_global_load_lds( \
    (const __attribute__((address_space(1))) unsigned int*)(gsrc), \
    (__attribute__((address_space(3))) unsigned int*)(ldst), 16, 0, 0)

__device__ __forceinline__ unsigned short f2bf(float x){
    unsigned u = __builtin_bit_cast(unsigned, x);
    u += 0x7fffu + ((u >> 16) & 1u);
    return (unsigned short)(u >> 16);
}
__device__ __forceinline__ float bf2f(unsigned short h){
    unsigned u = ((unsigned)h) << 16;
    return __builtin_bit_cast(float, u);
}

// ---------------- split X -> hi/lo bf16 ----------------
__global__ __launch_bounds__(256) void split_x(
    const float* __restrict__ X, ushort* __restrict__ Xh, ushort* __restrict__ Xl)
{
    size_t i = ((size_t)blockIdx.x * 256 + threadIdx.x) * 8;
    float4 a = *(const float4*)(X + i);
    float4 b = *(const float4*)(X + i + 4);
    float v[8] = {a.x, a.y, a.z, a.w, b.x, b.y, b.z, b.w};
    union { ushort us[8]; uint4 u; } hi, lo;
    #pragma unroll
    for (int j = 0; j < 8; ++j) {
        unsigned short h = f2bf(v[j]);
        hi.us[j] = h;
        lo.us[j] = f2bf(v[j] - bf2f(h));
    }
    *(uint4*)(Xh + i) = hi.u;
    *(uint4*)(Xl + i) = lo.u;
}

// ---------------- split W -> W^T hi/lo bf16 ----------------
__global__ __launch_bounds__(256) void split_w(
    const float* __restrict__ Wq, const float* __restrict__ Wk, const float* __restrict__ Wv,
    ushort* __restrict__ Wqh, ushort* __restrict__ Wql,
    ushort* __restrict__ Wkh, ushort* __restrict__ Wkl,
    ushort* __restrict__ Wvh)
{
    int u = blockIdx.x * 256 + threadIdx.x;
    int z   = u >> 15;
    int rem = u & 32767;
    int ko  = rem >> 8;
    int e   = rem & 255;
    const float* W = (z == 0) ? Wq : (z == 1) ? Wk : Wv;
    ushort* Oh = (z == 0) ? Wqh : (z == 1) ? Wkh : Wvh;
    ushort* Ol = (z == 0) ? Wql : Wkl;
    union { ushort us[8]; uint4 v; } hi, lo;
    #pragma unroll
    for (int j = 0; j < 8; ++j) {
        float wv = W[(size_t)(ko * 8 + j) * 256 + e];
        unsigned short h = f2bf(wv);
        hi.us[j] = h;
        lo.us[j] = f2bf(wv - bf2f(h));
    }
    *(uint4*)(Oh + (size_t)e * 1024 + ko * 8) = hi.v;
    if (z < 2) *(uint4*)(Ol + (size_t)e * 1024 + ko * 8) = lo.v;
}

// ---------------- QKV projection: R8 config (best measured): 128x128, (256,2), all-GLD16 ----------------
__global__ __launch_bounds__(256, 2) void qkv_proj(
    const ushort* __restrict__ Xh, const ushort* __restrict__ Xl,
    const ushort* __restrict__ Whq, const ushort* __restrict__ Wlq,
    const ushort* __restrict__ Whk, const ushort* __restrict__ Wlk,
    const ushort* __restrict__ Whv,
    const float* __restrict__ bq, const float* __restrict__ bk, const float* __restrict__ bv,
    ushort* __restrict__ Qh, ushort* __restrict__ Ql,
    ushort* __restrict__ Kh, ushort* __restrict__ Kl,
    ushort* __restrict__ Vt)
{
    __shared__ ushort Ah[4096], Al[4096], Bh[4096], Bl[4096];  // unit = kq*128 + row

    const int tid = threadIdx.x;
    const int lane = tid & 63, w = tid >> 6;
    const int ln = tid & 15, quad = (tid >> 4) & 3;
    const int wr = w >> 1, wc = w & 1;
    const int z = blockIdx.z;
    const int n0 = blockIdx.x * 128, m0 = blockIdx.y * 128;
    const ushort* Wh = (z == 0) ? Whq : (z == 1) ? Whk : Whv;
    const ushort* Wl = (z == 0) ? Wlq : Wlk;

    f32x4 acc[4][4];
    #pragma unroll
    for (int mi = 0; mi < 4; ++mi)
        #pragma unroll
        for (int ni = 0; ni < 4; ++ni) acc[mi][ni] = (f32x4){0.f, 0.f, 0.f, 0.f};

    const ushort* a0 = Xh + (size_t)(m0 + lane) * IDIM + w * 8;
    const ushort* a1 = Xh + (size_t)(m0 + 64 + lane) * IDIM + w * 8;
    const ushort* a0l = Xl + (size_t)(m0 + lane) * IDIM + w * 8;
    const ushort* a1l = Xl + (size_t)(m0 + 64 + lane) * IDIM + w * 8;
    const ushort* b0 = Wh + (size_t)(n0 + lane) * IDIM + w * 8;
    const ushort* b1 = Wh + (size_t)(n0 + 64 + lane) * IDIM + w * 8;
    const ushort* b0l = Wl + (size_t)(n0 + lane) * IDIM + w * 8;
    const ushort* b1l = Wl + (size_t)(n0 + 64 + lane) * IDIM + w * 8;
    ushort* dA0 = Ah + (size_t)(w * 128) * 8;
    ushort* dA1 = Ah + (size_t)(w * 128 + 64) * 8;
    ushort* dA0l = Al + (size_t)(w * 128) * 8;
    ushort* dA1l = Al + (size_t)(w * 128 + 64) * 8;
    ushort* dB0 = Bh + (size_t)(w * 128) * 8;
    ushort* dB1 = Bh + (size_t)(w * 128 + 64) * 8;
    ushort* dB0l = Bl + (size_t)(w * 128) * 8;
    ushort* dB1l = Bl + (size_t)(w * 128 + 64) * 8;

    for (int kk = 0; kk < IDIM; kk += 32) {
        GLD16(a0 + kk, dA0);
        GLD16(a1 + kk, dA1);
        GLD16(b0 + kk, dB0);
        GLD16(b1 + kk, dB1);
        if (z < 2) {
            GLD16(a0l + kk, dA0l);
            GLD16(a1l + kk, dA1l);
            GLD16(b0l + kk, dB0l);
            GLD16(b1l + kk, dB1l);
        }
        __syncthreads();

        short8 ah[4], al[4], bh[4], bl[4];
        #pragma unroll
        for (int mi = 0; mi < 4; ++mi) {
            int au = quad * 128 + wr * 64 + mi * 16 + ln;
            ah[mi] = *(const short8*)(Ah + au * 8);
            if (z < 2) al[mi] = *(const short8*)(Al + au * 8);
        }
        #pragma unroll
        for (int ni = 0; ni < 4; ++ni) {
            int bu = quad * 128 + wc * 64 + ni * 16 + ln;
            bh[ni] = *(const short8*)(Bh + bu * 8);
            if (z < 2) bl[ni] = *(const short8*)(Bl + bu * 8);
        }
        if (z < 2) {
            #pragma unroll
            for (int ni = 0; ni < 4; ++ni)
                #pragma unroll
                for (int mi = 0; mi < 4; ++mi) {
                    acc[mi][ni] = MFMA16(ah[mi], bh[ni], acc[mi][ni]);
                    acc[mi][ni] = MFMA16(ah[mi], bl[ni], acc[mi][ni]);
                    acc[mi][ni] = MFMA16(al[mi], bh[ni], acc[mi][ni]);
                }
        } else {
            #pragma unroll
            for (int ni = 0; ni < 4; ++ni)
                #pragma unroll
                for (int mi = 0; mi < 4; ++mi)
                    acc[mi][ni] = MFMA16(ah[mi], bh[ni], acc[mi][ni]);
        }
        __syncthreads();
    }

    if (z < 2) {
        ushort* OH = (z == 0) ? Qh : Kh;
        ushort* OL = (z == 0) ? Ql : Kl;
        const float* bias = (z == 0) ? bq : bk;
        const float scale = (z == 0) ? 46.16624130844683f : 1.0f;  // 32*log2(e)
        #pragma unroll
        for (int ni = 0; ni < 4; ++ni) {
            int col = n0 + wc * 64 + ni * 16 + ln;
            float bb = bias[col];
            #pragma unroll
            for (int mi = 0; mi < 4; ++mi)
                #pragma unroll
                for (int r = 0; r < 4; ++r) {
                    int row = m0 + wr * 64 + mi * 16 + quad * 4 + r;
                    float v = (acc[mi][ni][r] + bb) * scale;
                    unsigned short hh = f2bf(v);
                    OH[(size_t)row * EDIM + col] = hh;
                    OL[(size_t)row * EDIM + col] = f2bf(v - bf2f(hh));
                }
        }
    } else {
        #pragma unroll
        for (int ni = 0; ni < 4; ++ni) {
            int col = n0 + wc * 64 + ni * 16 + ln;
            float bb = bv[col];
            #pragma unroll
            for (int mi = 0; mi < 4; ++mi) {
                int rowb = m0 + wr * 64 + mi * 16 + quad * 4;
                union { ushort us[4]; uint2 v; } pk;
                #pragma unroll
                for (int r = 0; r < 4; ++r) pk.us[r] = f2bf(acc[mi][ni][r] + bb);
                *(uint2*)(Vt + (size_t)col * NROW + rowb) = pk.v;  // V^T[e][row]
            }
        }
    }
}

// ---------------- attention v3: BN=32 full-E staging, 2 barriers/t, 64 MFMA/t ----------------
// 512 blocks x 4 waves (q-split). Per t: 12 GLD16/wave stage Khi|Klo|V (48 KB),
// 1 barrier, 48 S-MFMA + softmax + 16 PV-MFMA, 1 barrier. 32 barriers total (was 192).
__global__ __launch_bounds__(256, 2) void attn(
    const ushort* __restrict__ Qh, const ushort* __restrict__ Ql,
    const ushort* __restrict__ Kh, const ushort* __restrict__ Kl,
    const ushort* __restrict__ Vt, ushort* __restrict__ Op, float* __restrict__ mlbuf)
{
    __shared__ ushort KhiL[8192];      // unit = kq*32 + c   (kq: e-octet 0..31, c: kv 0..31)
    __shared__ ushort KloL[8192];
    __shared__ ushort VsL[8192];       // unit = kq2*256 + e (kq2: kv-octet 0..3, e 0..255)
    __shared__ ushort Pall[4 * 544];   // per-wave P slab: unit = ko*17 + row (ko 0..3)

    const int tid = threadIdx.x;
    const int ln = tid & 15, quad = (tid >> 4) & 3, w = tid >> 6;
    ushort* Pw = Pall + w * 544;

    const int id = blockIdx.x;              // 512 = qt(32) x [b(4) x kvq(4)]
    const int cls = id & 15;
    const int b = cls >> 2, kvq = cls & 3;
    const int qt = id >> 4;
    const int qrow0w = b * NT + qt * 64 + w * 16;
    const int kvbase = b * NT + kvq * 512;

    // Q hi+lo fragments resident in registers
    short8 qh8[8], ql8[8];
    #pragma unroll
    for (int kc = 0; kc < 8; ++kc) {
        size_t qoff = (size_t)(qrow0w + ln) * EDIM + kc * 32 + quad * 8;
        qh8[kc] = *(const short8*)(Qh + qoff);
        ql8[kc] = *(const short8*)(Ql + qoff);
    }

    float m_r[4], l_r[4];
    #pragma unroll
    for (int r = 0; r < 4; ++r) { m_r[r] = -3e38f; l_r[r] = 0.f; }
    f32x4 o[16];
    #pragma unroll
    for (int ni = 0; ni < 16; ++ni) o[ni] = (f32x4){0.f, 0.f, 0.f, 0.f};

    #pragma unroll 1
    for (int t = 0; t < 16; ++t) {
        const int kv0 = kvbase + t * 32;

        // ---- stage K hi/lo + V for the whole 32-kv tile (12 GLD16/wave) ----
        #pragma unroll
        for (int r = 0; r < 4; ++r) {
            int u = r * 256 + tid;
            int c = u & 31, kq = u >> 5;
            size_t ksrc = (size_t)(kv0 + c) * EDIM + kq * 8;
            GLD16(Kh + ksrc, KhiL + (size_t)(r * 256 + (tid & ~63)) * 8);
            GLD16(Kl + ksrc, KloL + (size_t)(r * 256 + (tid & ~63)) * 8);
        }
        #pragma unroll
        for (int r = 0; r < 4; ++r) {
            int u = r * 256 + tid;
            int e = u & 255, kq2 = u >> 8;
            GLD16(Vt + (size_t)e * NROW + kv0 + kq2 * 8,
                  VsL + (size_t)(r * 256 + (tid & ~63)) * 8);
        }
        __syncthreads();

        // ---- S = Q'.K^T (16q x 32kv) ----
        f32x4 s[2];
        s[0] = (f32x4){0.f, 0.f, 0.f, 0.f};
        s[1] = (f32x4){0.f, 0.f, 0.f, 0.f};
        #pragma unroll
        for (int kc = 0; kc < 8; ++kc) {
            int kq = kc * 4 + quad;
            #pragma unroll
            for (int ni = 0; ni < 2; ++ni) {
                short8 bh = *(const short8*)(KhiL + (kq * 32 + ni * 16 + ln) * 8);
                short8 bl = *(const short8*)(KloL + (kq * 32 + ni * 16 + ln) * 8);
                s[ni] = MFMA16(qh8[kc], bh, s[ni]);
                s[ni] = MFMA16(qh8[kc], bl, s[ni]);
                s[ni] = MFMA16(ql8[kc], bh, s[ni]);
            }
        }

        // ---- online softmax (wave-local, rows in 16-lane groups) ----
        float mt[4];
        #pragma unroll
        for (int r = 0; r < 4; ++r) mt[r] = fmaxf(s[0][r], s[1][r]);
        #pragma unroll
        for (int mask = 1; mask < 16; mask <<= 1)
            #pragma unroll
            for (int r = 0; r < 4; ++r)
                mt[r] = fmaxf(mt[r], __shfl_xor(mt[r], mask));
        float alpha[4];
        #pragma unroll
        for (int r = 0; r < 4; ++r) {
            float mn = fmaxf(m_r[r], mt[r]);
            alpha[r] = exp2f(m_r[r] - mn);
            m_r[r] = mn;
        }
        float ls[4] = {0.f, 0.f, 0.f, 0.f};
        #pragma unroll
        for (int ni = 0; ni < 2; ++ni) {
            int colb = ni * 16 + ln;
            #pragma unroll
            for (int r = 0; r < 4; ++r) {
                float p = exp2f(s[ni][r] - m_r[r]);
                ls[r] += p;
                Pw[((colb >> 3) * 17 + quad * 4 + r) * 8 + (colb & 7)] = f2bf(p);
            }
        }
        #pragma unroll
        for (int mask = 1; mask < 16; mask <<= 1)
            #pragma unroll
            for (int r = 0; r < 4; ++r)
                ls[r] += __shfl_xor(ls[r], mask);
        #pragma unroll
        for (int r = 0; r < 4; ++r) l_r[r] = l_r[r] * alpha[r] + ls[r];
        #pragma unroll
        for (int ni = 0; ni < 16; ++ni)
            #pragma unroll
            for (int r = 0; r < 4; ++r) o[ni][r] *= alpha[r];

        // ---- O += P.V (k=32: one MFMA k-step; A from wave-private slab) ----
        short8 ap = *(const short8*)(Pw + (quad * 17 + ln) * 8);
        #pragma unroll
        for (int ni = 0; ni < 16; ++ni) {
            short8 bv8 = *(const short8*)(VsL + (quad * 256 + ni * 16 + ln) * 8);
            o[ni] = MFMA16(ap, bv8, o[ni]);
        }
        __syncthreads();
    }

    // ---- epilogue: bf16 partial + (m,l) ----
    const int p = (b * 32 + qt) * 4 + kvq;
    if (ln == 0) {
        #pragma unroll
        for (int r = 0; r < 4; ++r) {
            int row = w * 16 + quad * 4 + r;
            *(float2*)(mlbuf + ((size_t)p * 64 + row) * 2) = make_float2(m_r[r], l_r[r]);
        }
    }
    #pragma unroll
    for (int ni = 0; ni < 16; ++ni)
        #pragma unroll
        for (int r = 0; r < 4; ++r) {
            int row = w * 16 + quad * 4 + r;
            Op[(size_t)p * 16384 + row * 256 + ni * 16 + ln] = f2bf(o[ni][r]);
        }
}

// ---------------- final merge of 4 kv-quarter partials ----------------
__global__ __launch_bounds__(256) void attn_merge(
    const ushort* __restrict__ Op, const float* __restrict__ mlbuf, float* __restrict__ out)
{
    const int bid = blockIdx.x, t = threadIdx.x;   // 512 blocks: b(4) x qt(32) x rg(4)
    const int b = bid >> 7, qt = (bid >> 2) & 31, rg = bid & 3;
    const int row = rg * 16 + (t >> 4);
    const int e0 = (t & 15) * 16;
    const int pb = (b * 32 + qt) * 4;
    float mv[4], lv[4];
    float M = -3e38f;
    #pragma unroll
    for (int w2 = 0; w2 < 4; ++w2) {
        float2 ml = *(const float2*)(mlbuf + ((size_t)(pb + w2) * 64 + row) * 2);
        mv[w2] = ml.x; lv[w2] = ml.y;
        M = fmaxf(M, ml.x);
    }
    float sc[4], denom = 0.f;
    #pragma unroll
    for (int w2 = 0; w2 < 4; ++w2) {
        sc[w2] = exp2f(mv[w2] - M);
        denom += sc[w2] * lv[w2];
    }
    float inv = 1.0f / denom;
    #pragma unroll
    for (int w2 = 0; w2 < 4; ++w2) sc[w2] *= inv;

    float acc[16] = {};
    #pragma unroll
    for (int w2 = 0; w2 < 4; ++w2) {
        const ushort* src = Op + (size_t)(pb + w2) * 16384 + row * 256 + e0;
        #pragma unroll
        for (int c = 0; c < 2; ++c) {
            union { ushort us[8]; uint4 v; } u;
            u.v = *(const uint4*)(src + c * 8);
            #pragma unroll
            for (int j = 0; j < 8; ++j)
                acc[c * 8 + j] += sc[w2] * bf2f(u.us[j]);
        }
    }
    float* op = out + ((size_t)b * NT + qt * 64 + row) * EDIM + e0;
    #pragma unroll
    for (int g = 0; g < 4; ++g)
        *(float4*)(op + g * 4) = make_float4(acc[g*4], acc[g*4+1], acc[g*4+2], acc[g*4+3]);
}

extern "C" void kernel_launch(void* const* d_in, const int* in_sizes, int n_in,
                              void* d_out, int out_size, void* d_ws, size_t ws_size,
                              hipStream_t stream) {
    const float* x  = (const float*)d_in[0];
    const float* Wq = (const float*)d_in[1];
    const float* bq = (const float*)d_in[2];
    const float* Wk = (const float*)d_in[3];
    const float* bk = (const float*)d_in[4];
    const float* Wv = (const float*)d_in[5];
    const float* bv = (const float*)d_in[6];
    float* out = (float*)d_out;

    const size_t NX = (size_t)NROW * IDIM;           // 8.4M elems
    const size_t NE = (size_t)NB * NT * EDIM;        // 2M elems
    ushort* Xh = (ushort*)d_ws;                      // 16.8 MB
    ushort* Xl = Xh + NX;                            // 16.8 MB
    ushort* Qh = Xl + NX;
    ushort* Ql = Qh + NE;
    ushort* Kh = Ql + NE;
    ushort* Kl = Kh + NE;
    ushort* Vt = Kl + NE;                            // [256][8192]
    ushort* Wqh = Vt + NE;
    ushort* Wql = Wqh + 256 * 1024;
    ushort* Wkh = Wql + 256 * 1024;
    ushort* Wkl = Wkh + 256 * 1024;
    ushort* Wvh = Wkl + 256 * 1024;                  // total ~56.2 MB
    // Op/mlb alias Xh/Xl (dead after qkv_proj; same-stream ordering)
    ushort* Op  = Xh;                                // 512 x 64 x 256 bf16 (16.8 MB)
    float*  mlb = (float*)(Xh + (size_t)512 * 16384);

    split_x<<<4096, 256, 0, stream>>>(x, Xh, Xl);
    split_w<<<384, 256, 0, stream>>>(Wq, Wk, Wv, Wqh, Wql, Wkh, Wkl, Wvh);
    qkv_proj<<<dim3(2, 64, 3), 256, 0, stream>>>(Xh, Xl, Wqh, Wql, Wkh, Wkl, Wvh,
                                                 bq, bk, bv, Qh, Ql, Kh, Kl, Vt);
    attn<<<512, 256, 0, stream>>>(Qh, Ql, Kh, Kl, Vt, Op, mlb);
    attn_merge<<<512, 256, 0, stream>>>(Op, mlb, out);
}